// Round 2
// 91.699 us; speedup vs baseline: 1.0155x; 1.0155x over previous
//
#include <hip/hip_runtime.h>

#define S_LEN 20
#define G_CNT 64
#define NPED  128
#define N_TOT 8192
#define M_PTS 200
#define K_GRP 2560            // S_LEN * NPED
#define MLP_DIM 1024

// ---------------------------------------------------------------------------
// Single fused kernel. Grid = 256 blocks = (group g, ped-quarter q); block
// (g,q) owns pedestrians [q*32, q*32+32) of group g for the FULL 20 timesteps,
// so it computes their total cnt_a and cnt_s locally (no cross-block
// reduction, no workspace, no second dispatch) and then evaluates both MLPs
// for its 64 outputs (32 peds x 2 MLPs).
//
// Output layout: [0,8192) scores1 (agent), [8192,16384) scores2 (scene).
// ---------------------------------------------------------------------------
__global__ __launch_bounds__(512) void fused_kernel(
    const float2* __restrict__ traj,          // (S, N) as float2
    const int*    __restrict__ seq_scene_ids, // (G,)
    const float2* __restrict__ scenes,        // (8, 200) as float2
    const float* __restrict__ w1a, const float* __restrict__ b1a,
    const float* __restrict__ w2a, const float* __restrict__ b2a,
    const float* __restrict__ w1s, const float* __restrict__ b1s,
    const float* __restrict__ w2s, const float* __restrict__ b2s,
    float* __restrict__ out)
{
    const int bx  = blockIdx.x;
    const int g   = bx >> 2;
    const int q   = bx & 3;
    const int tid = threadIdx.x;

    __shared__ float2 P[K_GRP];      // P[t*128+ped] = traj[t, g*128+ped]
    __shared__ float2 SC[M_PTS];
    __shared__ int    red[512];
    __shared__ int    diffA[130];    // residue difference array (129 used)
    __shared__ int    baseS;
    __shared__ int    cntA[32], cntS[32];
    __shared__ float  part[4][64];

    // ---- stage loads: full group tile (20 x 128 float2 = 20 KB) ----
    #pragma unroll
    for (int r = 0; r < 5; ++r) {
        int idx = tid + r*512;               // [0,2560)
        int t = idx >> 7, ped = idx & 127;
        P[idx] = traj[t*N_TOT + g*NPED + ped];
    }
    {
        int sid = seq_scene_ids[g];
        if (tid < M_PTS) SC[tid] = scenes[sid*M_PTS + tid];
        if (tid <= 128) diffA[tid] = 0;
        if (tid == 129) baseS = 0;
    }
    __syncthreads();

    // ---- phase A: agent-agent counts (0 < d2 < 0.0625) for our 32 peds ----
    // thread = (j = tid&31 local ped, p = tid>>5 i-chunk of 8); 160 pairs/thread
    {
        const unsigned thrB = __float_as_uint(0.0625f) - 1u;
        const int j = q*32 + (tid & 31);
        const int p = tid >> 5;              // [0,16)
        int c = 0;
        for (int sl = 0; sl < S_LEN; ++sl) {
            float2 xj = P[sl*128 + j];
            #pragma unroll
            for (int ii = 0; ii < 8; ++ii) {
                float2 xi = P[sl*128 + p*8 + ii];   // half-wave-uniform -> LDS broadcast
                float dx = xj.x - xi.x;
                float dy = xj.y - xi.y;
                // match numpy: round dx*dx and dy*dy separately, then add (no fma)
                float sq = __fadd_rn(__fmul_rn(dx, dx), __fmul_rn(dy, dy));
                // (sq > 0) && (sq < thr): positive-float bit compare
                c += (int)((__float_as_uint(sq) - 1u) < thrB);
            }
        }
        red[tid] = c;
    }

    // ---- phase B: scene counts via run decomposition over ALL 2560 pi ----
    // (duplicated across the 4 q-blocks of a group; ~5 iters/thread, cheap)
    for (int pil = tid; pil < K_GRP; pil += 512) {
        float2 pp = P[pil];
        int a0 = pil*200, a1 = a0 + 200;
        int s0 = a0 / K_GRP;
        int sL = (a1 - 1) / K_GRP;
        int bnd = (sL > s0) ? sL*K_GRP : a1;

        {   // run 1: scene point s0, f in [a0, bnd)
            float dx = SC[s0].x - pp.x, dy = SC[s0].y - pp.y;
            float d2 = __fadd_rn(__fmul_rn(dx, dx), __fmul_rn(dy, dy));
            if (__float_as_uint(d2) < 0x3f800000u) {   // d2 < 1.0f
                int L = bnd - a0;
                int full = L >> 7, rem = L & 127;
                if (full) atomicAdd(&baseS, full);
                if (rem) {
                    int st = a0 & 127, en = st + rem;
                    atomicAdd(&diffA[st], 1);
                    if (en <= 128) atomicAdd(&diffA[en], -1);
                    else { atomicAdd(&diffA[0], 1); atomicAdd(&diffA[en-128], -1); }
                }
            }
        }
        if (sL > s0) {   // run 2: scene point sL, f in [bnd, a1)
            float dx = SC[sL].x - pp.x, dy = SC[sL].y - pp.y;
            float d2 = __fadd_rn(__fmul_rn(dx, dx), __fmul_rn(dy, dy));
            if (__float_as_uint(d2) < 0x3f800000u) {
                int L = a1 - bnd;
                int full = L >> 7, rem = L & 127;
                if (full) atomicAdd(&baseS, full);
                if (rem) {
                    int st = bnd & 127, en = st + rem;
                    atomicAdd(&diffA[st], 1);
                    if (en <= 128) atomicAdd(&diffA[en], -1);
                    else { atomicAdd(&diffA[0], 1); atomicAdd(&diffA[en-128], -1); }
                }
            }
        }
    }
    __syncthreads();

    // ---- finalize counts (wave 0: cnt_a reduce; wave 1: cnt_s prefix) ----
    if (tid < 32) {
        int c = 0;
        #pragma unroll
        for (int pp = 0; pp < 16; ++pp) c += red[pp*32 + tid];
        cntA[tid] = c;
    }
    if (tid >= 64 && tid < 96) {
        int pl = tid - 64;
        int pg = q*32 + pl;                  // ped index within group
        int e = 0;
        for (int u = 0; u < 128; ++u) {
            int dv = diffA[u];               // LDS broadcast
            if (u <= pg) e += dv;
        }
        cntS[pl] = baseS + e;
    }
    __syncthreads();

    // ---- MLP: 64 outputs (lane = m*32+ped), wv = quarter of hidden dim ----
    // Accumulation topology identical to the verified 2-kernel version:
    // 4 sequential chunks of 256, then p0+p1+p2+p3+b2 (absmax stays 0.0).
    if (tid < 256) {
        const int lane = tid & 63;
        const int wv   = tid >> 6;
        const int m    = lane >> 5;          // 0 = agent, 1 = scene
        const int ped  = lane & 31;
        const float* w1 = m ? w1s : w1a;
        const float* b1 = m ? b1s : b1a;
        const float* w2 = m ? w2s : w2a;
        const float c = (float)(m ? cntS[ped] : cntA[ped]);   // counts < 2^24, exact

        float acc = 0.f;
        const int k0 = wv*256;
        #pragma unroll 8
        for (int k = k0; k < k0 + 256; ++k) {
            float h = fmaxf(__fadd_rn(__fmul_rn(c, w1[k]), b1[k]), 0.f);
            acc = __fadd_rn(acc, __fmul_rn(h, w2[k]));
        }
        part[wv][lane] = acc;
    }
    __syncthreads();
    if (tid < 64) {
        const int m = tid >> 5, ped = tid & 31;
        const float b2v = m ? b2s[0] : b2a[0];
        out[m*N_TOT + g*NPED + q*32 + ped] =
            part[0][tid] + part[1][tid] + part[2][tid] + part[3][tid] + b2v;
    }
}

extern "C" void kernel_launch(void* const* d_in, const int* in_sizes, int n_in,
                              void* d_out, int out_size, void* d_ws, size_t ws_size,
                              hipStream_t stream)
{
    const float2* traj   = (const float2*)d_in[0];
    // d_in[1] = traj_rel (unused), d_in[2] = seq_start_end (groups are uniform)
    const int*    ssi    = (const int*)d_in[3];
    const float2* scenes = (const float2*)d_in[4];
    const float*  w1a    = (const float*)d_in[5];
    const float*  b1a    = (const float*)d_in[6];
    const float*  w2a    = (const float*)d_in[7];
    const float*  b2a    = (const float*)d_in[8];
    const float*  w1s    = (const float*)d_in[9];
    const float*  b1s    = (const float*)d_in[10];
    const float*  w2s    = (const float*)d_in[11];
    const float*  b2s    = (const float*)d_in[12];

    // workspace unused: each block computes its 32 peds' totals locally
    fused_kernel<<<dim3(G_CNT*4), dim3(512), 0, stream>>>(
        traj, ssi, scenes,
        w1a, b1a, w2a, b2a, w1s, b1s, w2s, b2s, (float*)d_out);
}